// Round 1
// baseline (214.010 us; speedup 1.0000x reference)
//
#include <hip/hip_runtime.h>
#include <math.h>

#define NT 16384
#define DIM 2048
#define NE 64
#define TK 8

typedef _Float16 f16_t;
typedef _Float16 half8 __attribute__((ext_vector_type(8)));
typedef float floatx16 __attribute__((ext_vector_type(16)));

// ---------------- Prep: W fp32 -> f16 hi/lo in 32x32x16 B-fragment order; block 64 = scalar chain ----------------
// B-frag layout (verified): lane holds B[n=lane&31][k=8*(lane>>5)+j], one 16B half8 per frag.
__global__ __launch_bounds__(256) void prep_kernel(const float* __restrict__ w,
                                                   const float* __restrict__ expert_loads,
                                                   const float* __restrict__ bias_strength,
                                                   float* __restrict__ ws_bias,
                                                   float* __restrict__ ws_batch,
                                                   f16_t* __restrict__ whi,
                                                   f16_t* __restrict__ wlo,
                                                   float* __restrict__ out_bias_strength) {
    if (blockIdx.x == 64) {
        int e = threadIdx.x;
        if (e < 64) {
            float load = expert_loads[e];
            float s = load;
            #pragma unroll
            for (int off = 32; off >= 1; off >>= 1) s += __shfl_xor(s, off, 64);
            s = fmaxf(s, 1e-8f);
            float q = load / s;
            const float t = 1.0f / 64.0f;
            float kl = t * (logf(t) - logf(fmaxf(q, 1e-8f)));
            #pragma unroll
            for (int off = 32; off >= 1; off >>= 1) kl += __shfl_xor(kl, off, 64);
            float as = 1.0f / (1.0f + expf(-10.0f * kl));
            float nbs = 0.9f * bias_strength[0] + 0.1f * as;
            ws_bias[e] = tanhf((q - t) * 64.0f) * nbs;
            ws_batch[e] = 0.0f;
            if (e == 0) out_bias_strength[0] = nbs;
        }
        return;
    }
    int idx = blockIdx.x * 256 + threadIdx.x;   // (c16, tile, lane)
    int lane = idx & 63;
    int tile = (idx >> 6) & 1;
    int c    = idx >> 7;
    int n = tile * 32 + (lane & 31);
    int k = c * 16 + (lane >> 5) * 8;
    const float* src = w + (size_t)n * DIM + k;
    float4 a = *(const float4*)src;
    float4 b = *(const float4*)(src + 4);
    float v[8] = {a.x, a.y, a.z, a.w, b.x, b.y, b.z, b.w};
    half8 h, l;
    #pragma unroll
    for (int j = 0; j < 8; ++j) {
        f16_t hh = (f16_t)v[j];
        h[j] = hh;
        l[j] = (f16_t)(v[j] - (float)hh);
    }
    *(half8*)(whi + (size_t)idx * 8) = h;
    *(half8*)(wlo + (size_t)idx * 8) = l;
}

// ---------------- Main: async gload_lds double-buffered split-f16 MFMA GEMM + noise + bias + top-8 + softmax ----
// 512 thr = 8 waves = split-K x8. Tile 32 tokens x 64 experts. Grid 512 = 2 blocks/CU, 4 waves/SIMD.
// Pipeline (m201-style): raw fp32 staged by global_load_lds width=16 (no VGPR round-trip, no staging VALU),
// 2 LDS buffers, raw s_barrier + counted vmcnt (NEVER __syncthreads in the K-loop, which would drain vmcnt(0)).
// B-frag loads are issued BEFORE STAGE(s+1) so in-order vmcnt retirement gives:
//   outstanding at wait = [4 gload(s) old] [8 B-frag] [4 gload(s+1) new] -> vmcnt(12) retires window s only,
// and the compiler's pre-MFMA wait for B-frags lands at vmcnt(4), keeping the prefetch in flight.
// hi/lo split (RNE, identical numerics to verified version) moved into the consumer.
__global__ __launch_bounds__(512, 4) void router_main(const float* __restrict__ x,
                                                      const f16_t* __restrict__ whi,
                                                      const f16_t* __restrict__ wlo,
                                                      const float* __restrict__ noise,
                                                      const float* __restrict__ ws_bias,
                                                      float* __restrict__ ws_batch,
                                                      float* __restrict__ out) {
    // 69,632 B: stage[2][32][260] f32 (66,560 B) overlaid by part[8][32][68] f32 afterwards
    __shared__ float smem[17408];
    __shared__ float bias_sh[64];
    __shared__ float loads_sh[64];

    const int tid = threadIdx.x;
    const int wv  = tid >> 6;        // 0..7: split-K partition (chunks s*16 + wv*2 + {0,1})
    const int L   = tid & 63;
    const int r   = L & 31;          // A-frag row (token within tile)
    const int kh  = L >> 5;
    const int token0 = blockIdx.x * 32;

    if (tid < 64) { bias_sh[tid] = ws_bias[tid]; loads_sh[tid] = 0.0f; }

    const half8* whi8 = (const half8*)whi;
    const half8* wlo8 = (const half8*)wlo;

    floatx16 acc0, acc1;
    #pragma unroll
    for (int i = 0; i < 16; ++i) { acc0[i] = 0.0f; acc1[i] = 0.0f; }

    // Issue one window (32 rows x 1KB) of raw fp32 into LDS buffer S&1.
    // Dest is wave-uniform row base + lane*16B (gload_lds constraint); row stride 260 f32 = 1040 B.
    auto STAGE = [&](int S) {
        const int b_ = S & 1;
        #pragma unroll
        for (int q = 0; q < 4; ++q) {
            const int row_ = wv + q * 8;
            const float* gsrc = x + (size_t)(token0 + row_) * DIM + S * 256 + L * 4;
            float* ldst = (float*)(smem + b_ * 8320 + row_ * 260);
            __builtin_amdgcn_global_load_lds(
                (const __attribute__((address_space(1))) unsigned int*)gsrc,
                (__attribute__((address_space(3))) unsigned int*)ldst,
                16, 0, 0);
        }
    };

    STAGE(0);

    #pragma unroll
    for (int s = 0; s < 8; ++s) {
        // B fragments for this window's two chunks (L2-resident, 8 x 16B). MUST precede STAGE(s+1).
        half8 bf[8];
        {
            const int c0 = s * 16 + wv * 2;
            const int i0 = (c0 * 2) * 64 + L;
            const int i1 = ((c0 + 1) * 2) * 64 + L;
            bf[0] = whi8[i0];      bf[1] = whi8[i0 + 64];
            bf[2] = wlo8[i0];      bf[3] = wlo8[i0 + 64];
            bf[4] = whi8[i1];      bf[5] = whi8[i1 + 64];
            bf[6] = wlo8[i1];      bf[7] = wlo8[i1 + 64];
        }
        if (s < 7) {
            STAGE(s + 1);
            asm volatile("s_waitcnt vmcnt(12)" ::: "memory");  // window-s gloads retired; 8 B + 4 prefetch alive
        } else {
            asm volatile("s_waitcnt vmcnt(8)" ::: "memory");   // last window: only 8 B-frags newer
        }
        __builtin_amdgcn_sched_barrier(0);
        __builtin_amdgcn_s_barrier();        // (A) all waves' window-s rows visible

        const float* xrow = smem + (s & 1) * 8320 + r * 260 + wv * 32 + kh * 8;
        #pragma unroll
        for (int cc = 0; cc < 2; ++cc) {
            float4 f0 = *(const float4*)(xrow + cc * 16);
            float4 f1 = *(const float4*)(xrow + cc * 16 + 4);
            float v[8] = {f0.x, f0.y, f0.z, f0.w, f1.x, f1.y, f1.z, f1.w};
            half8 ah, al;
            #pragma unroll
            for (int j = 0; j < 8; ++j) {
                f16_t hh = (f16_t)v[j];              // RNE hi (matches verified numerics)
                ah[j] = hh;
                al[j] = (f16_t)(v[j] - (float)hh);   // RNE lo
            }
            acc0 = __builtin_amdgcn_mfma_f32_32x32x16_f16(ah, bf[cc * 4 + 0], acc0, 0, 0, 0);
            acc1 = __builtin_amdgcn_mfma_f32_32x32x16_f16(ah, bf[cc * 4 + 1], acc1, 0, 0, 0);
            acc0 = __builtin_amdgcn_mfma_f32_32x32x16_f16(al, bf[cc * 4 + 0], acc0, 0, 0, 0);
            acc1 = __builtin_amdgcn_mfma_f32_32x32x16_f16(al, bf[cc * 4 + 1], acc1, 0, 0, 0);
            acc0 = __builtin_amdgcn_mfma_f32_32x32x16_f16(ah, bf[cc * 4 + 2], acc0, 0, 0, 0);
            acc1 = __builtin_amdgcn_mfma_f32_32x32x16_f16(ah, bf[cc * 4 + 3], acc1, 0, 0, 0);
        }
        __builtin_amdgcn_s_barrier();        // (B) buf[s&1] fully consumed -> STAGE(s+2) may overwrite
    }

    // Last barrier (B) guarantees all staging reads done; reuse staging region as part[].
    // C/D layout (verified m74/m101): col=lane&31, row=(reg&3)+8*(reg>>2)+4*kh
    #pragma unroll
    for (int reg = 0; reg < 16; ++reg) {
        int row = (reg & 3) + 8 * (reg >> 2) + 4 * kh;
        smem[wv * 2176 + row * 68 + r]      = acc0[reg];
        smem[wv * 2176 + row * 68 + 32 + r] = acc1[reg];
    }
    __syncthreads();

    // Split-K reduce + noise + bias -> final logits into part[0]
    #pragma unroll
    for (int p = 0; p < 4; ++p) {
        int o = tid + p * 512;               // 0..2047
        int t = o >> 6, e = o & 63;
        float sum = 0.0f;
        #pragma unroll
        for (int q = 0; q < 8; ++q) sum += smem[q * 2176 + t * 68 + e];
        sum += noise[(size_t)(token0 + t) * NE + e] * 0.01f - bias_sh[e];
        smem[t * 68 + e] = sum;              // own slot; no cross-thread hazard
    }
    __syncthreads();

    // Top-8 (strict '>' keeps lower index on ties, matching jax.lax.top_k) + softmax + load scatter
    if (tid < 32) {
        int t = tid;
        float tv[TK]; int ti_[TK];
        #pragma unroll
        for (int j = 0; j < TK; ++j) { tv[j] = -INFINITY; ti_[j] = 0; }
        for (int e = 0; e < NE; ++e) {
            float v = smem[t * 68 + e]; int id = e;
            #pragma unroll
            for (int j = 0; j < TK; ++j) {
                bool gt = v > tv[j];
                float nv = gt ? v : tv[j];
                int   ni = gt ? id : ti_[j];
                float ov = gt ? tv[j] : v;
                int   oi = gt ? ti_[j] : id;
                tv[j] = nv; ti_[j] = ni; v = ov; id = oi;
            }
        }
        float m = tv[0], ssum = 0.0f, wvv[TK];
        #pragma unroll
        for (int j = 0; j < TK; ++j) { wvv[j] = expf(tv[j] - m); ssum += wvv[j]; }
        float inv = 1.0f / ssum;
        size_t gt_ = (size_t)(token0 + t);
        #pragma unroll
        for (int j = 0; j < TK; ++j) {
            float wgt = wvv[j] * inv;
            out[gt_ * TK + j] = (float)ti_[j];
            out[(size_t)NT * TK + gt_ * TK + j] = wgt;
            atomicAdd(&loads_sh[ti_[j]], wgt);
        }
    }
    __syncthreads();
    if (tid < 64) atomicAdd(&ws_batch[tid], loads_sh[tid]);
}

// ---------------- EMA load update ----------------
__global__ __launch_bounds__(64) void finalize_kernel(const float* __restrict__ expert_loads,
                                                      const float* __restrict__ ws_batch,
                                                      float* __restrict__ out_loads) {
    int e = threadIdx.x;
    out_loads[e] = 0.999f * expert_loads[e] + 0.001f * (ws_batch[e] / (float)NT);
}

extern "C" void kernel_launch(void* const* d_in, const int* in_sizes, int n_in,
                              void* d_out, int out_size, void* d_ws, size_t ws_size,
                              hipStream_t stream) {
    const float* x     = (const float*)d_in[0];  // [16384, 2048]
    const float* rw    = (const float*)d_in[1];  // [64, 2048]
    const float* loads = (const float*)d_in[2];  // [64]
    const float* bs    = (const float*)d_in[3];  // [1]
    const float* noise = (const float*)d_in[4];  // [16384, 64]
    float* out = (float*)d_out;                  // [131072 idx | 131072 w | 64 loads | 1 bias]
    float* ws  = (float*)d_ws;
    float* ws_bias  = ws;
    float* ws_batch = ws + 64;
    f16_t* whi = (f16_t*)(ws + 128);             // 16384 frags x 8 halves = 256 KB
    f16_t* wlo = whi + (size_t)16384 * 8;        // another 256 KB

    prep_kernel<<<65, 256, 0, stream>>>(rw, loads, bs, ws_bias, ws_batch, whi, wlo,
                                        out + (size_t)NT * TK * 2 + NE);
    router_main<<<NT / 32, 512, 0, stream>>>(x, whi, wlo, noise, ws_bias, ws_batch, out);
    finalize_kernel<<<1, 64, 0, stream>>>(loads, ws_batch, out + (size_t)NT * TK * 2);
}